// Round 6
// baseline (91.573 us; speedup 1.0000x reference)
//
#include <hip/hip_runtime.h>
#include <hip/hip_bf16.h>

typedef __bf16 bf16x8 __attribute__((ext_vector_type(8)));
typedef float  f32x4  __attribute__((ext_vector_type(4)));

#define IN_F   4096
#define OUT_F  4096
#define RANK   32

__device__ __forceinline__ bf16x8 cvt8(float4 a, float4 b) {
    bf16x8 r;
    r[0] = (__bf16)a.x; r[1] = (__bf16)a.y; r[2] = (__bf16)a.z; r[3] = (__bf16)a.w;
    r[4] = (__bf16)b.x; r[5] = (__bf16)b.y; r[6] = (__bf16)b.z; r[7] = (__bf16)b.w;
    return r;
}

// ---------------- Kernel 1: H partials = X @ V^T (UNCHANGED from R5) ----------------
template <int KS>
__global__ __launch_bounds__(256, 2)
void lora_h(const float* __restrict__ X, const float* __restrict__ S,
            const float* __restrict__ V, float* __restrict__ Hpart)
{
    constexpr int F  = IN_F / KS;
    constexpr int NC = (F / 2) / 512;

    __shared__ float Hp[2][4][16][RANK + 1];

    const int tid  = threadIdx.x;
    const int wave = tid >> 6;
    const int lane = tid & 63;
    const int rh   = wave & 1;
    const int fh   = wave >> 1;
    const int row  = lane & 15;
    const int kg   = lane >> 4;

    const int t0 = blockIdx.x * 64;

    f32x4 acc[4] = {};

    for (int c = 0; c < NC; ++c) {
        const int fbase = blockIdx.y * F + fh * (F / 2) + c * 512 + kg * 8;

        bf16x8 va[16];
        #pragma unroll
        for (int s = 0; s < 16; ++s) {
            const float4* vp = reinterpret_cast<const float4*>(
                V + (size_t)(rh * 16 + row) * IN_F + fbase + s * 32);
            va[s] = cvt8(vp[0], vp[1]);
        }

        #pragma unroll
        for (int tt = 0; tt < 4; ++tt) {
            const float* xr = X + (size_t)(t0 + tt * 16 + row) * IN_F + fbase;
            float4 xa[16][2];
            #pragma unroll
            for (int s = 0; s < 16; ++s) {
                const float4* xp = reinterpret_cast<const float4*>(xr + s * 32);
                xa[s][0] = xp[0];
                xa[s][1] = xp[1];
            }
            #pragma unroll
            for (int s = 0; s < 16; ++s) {
                bf16x8 xb = cvt8(xa[s][0], xa[s][1]);
                acc[tt] = __builtin_amdgcn_mfma_f32_16x16x32_bf16(va[s], xb, acc[tt], 0, 0, 0);
            }
        }
    }

    #pragma unroll
    for (int tt = 0; tt < 4; ++tt)
        #pragma unroll
        for (int j = 0; j < 4; ++j)
            Hp[fh][tt][row][rh * 16 + kg * 4 + j] = acc[tt][j];
    __syncthreads();

    float* dst = Hpart + ((size_t)blockIdx.y * 512 + blockIdx.x * 4) * 512;
    for (int i = tid; i < 4 * 16 * RANK; i += 256) {
        int tok = i >> 5, r = i & 31;
        float s = Hp[0][tok >> 4][tok & 15][r] + Hp[1][tok >> 4][tok & 15][r];
        dst[i] = s * S[r];
    }
}

// ---------------- Kernel 2: Out = H @ U^T, LDS-staged contiguous stores ----------------
// grid 2048, block 256 (4 waves). Block b: token-tile tt = b>>2 (16 tokens),
// col-quarter cq = b&3 (1024 cols). Per 256-col group g: MFMA -> LDS T[16][260],
// then each wave stores 4 full rows as float4/lane = 1KB contiguous per instruction.
__global__ __launch_bounds__(256, 4)
void lora_out(const float* __restrict__ Hpart, const float* __restrict__ U,
              float* __restrict__ Out, int nks)
{
    __shared__ float Hs[16][RANK + 1];
    __shared__ float T[16][260];           // 260 % 32 = 4 -> kg groups 2-way max (free)

    const int tid  = threadIdx.x;
    const int wave = tid >> 6;
    const int lane = tid & 63;
    const int row  = lane & 15;
    const int kg   = lane >> 4;

    const int tt = blockIdx.x >> 2;
    const int cq = blockIdx.x & 3;
    const int t0 = tt * 16;

    // reduce K-split partials for this token tile (512 elements over 256 thr)
    for (int i = tid; i < 16 * RANK; i += 256) {
        float s = 0.f;
        for (int k = 0; k < nks; ++k)
            s += Hpart[((size_t)k * 512 + tt) * 512 + i];
        Hs[i >> 5][i & 31] = s;
    }
    __syncthreads();

    // A fragment: token = row, k(rank) = kg*8+j
    bf16x8 ha;
    #pragma unroll
    for (int j = 0; j < 8; ++j) ha[j] = (__bf16)Hs[row][kg * 8 + j];

    const float* ub = U + (size_t)(cq * 1024 + wave * 16 + row) * RANK + kg * 8;

    for (int g = 0; g < 4; ++g) {          // 256 out-cols per group
        // batch-load 4 U tiles (tile b covers col_local (b*4+wave)*16)
        float4 u0[4], u1[4];
        #pragma unroll
        for (int b = 0; b < 4; ++b) {
            const float4* up = reinterpret_cast<const float4*>(
                ub + (size_t)(g * 256 + b * 64) * RANK);
            u0[b] = up[0];
            u1[b] = up[1];
        }
        #pragma unroll
        for (int b = 0; b < 4; ++b) {
            bf16x8 bu = cvt8(u0[b], u1[b]);
            f32x4 d = {0.f, 0.f, 0.f, 0.f};
            d = __builtin_amdgcn_mfma_f32_16x16x32_bf16(ha, bu, d, 0, 0, 0);
            // D: col(out-feature within 16) = row, token = kg*4+j
            int cl = (b * 4 + wave) * 16 + row;
            #pragma unroll
            for (int j = 0; j < 4; ++j)
                T[kg * 4 + j][cl] = d[j];
        }
        __syncthreads();

        // contiguous stores: wave w -> rows w*4..w*4+3; lane -> 4 consecutive cols
        #pragma unroll
        for (int r = 0; r < 4; ++r) {
            int trow = wave * 4 + r;
            float4 vv = *reinterpret_cast<const float4*>(&T[trow][lane * 4]);
            *reinterpret_cast<float4*>(
                Out + (size_t)(t0 + trow) * OUT_F + cq * 1024 + g * 256 + lane * 4) = vv;
        }
        __syncthreads();                   // protect T before next group's writes
    }
}

extern "C" void kernel_launch(void* const* d_in, const int* in_sizes, int n_in,
                              void* d_out, int out_size, void* d_ws, size_t ws_size,
                              hipStream_t stream) {
    const float* X = (const float*)d_in[0];
    const float* U = (const float*)d_in[1];
    const float* S = (const float*)d_in[2];
    const float* V = (const float*)d_in[3];
    float* Out = (float*)d_out;
    float* Hpart = (float*)d_ws;

    if (ws_size >= (size_t)4 * 1024 * 1024) {
        lora_h<4><<<dim3(128, 4), 256, 0, stream>>>(X, S, V, Hpart);
        lora_out<<<2048, 256, 0, stream>>>(Hpart, U, Out, 4);
    } else {
        lora_h<1><<<dim3(128, 1), 256, 0, stream>>>(X, S, V, Hpart);
        lora_out<<<2048, 256, 0, stream>>>(Hpart, U, Out, 1);
    }
}